// Round 1
// baseline (1287.952 us; speedup 1.0000x reference)
//
#include <hip/hip_runtime.h>
#include <hip/hip_bf16.h>
#include <cstddef>

#define BATCH   16
#define SEQ     1024
#define D_MODEL 128
#define D_STATE 16
#define D_CONVK 4
#define D_INNER 256
#define N_LAYERS 2
#define NTOK    (BATCH*SEQ)   /* 16384 */
#define LN_EPS  1e-5f

__device__ __forceinline__ float siluf(float v){ return v / (1.f + __expf(-v)); }
__device__ __forceinline__ float softplusf(float x){ return x > 20.f ? x : log1pf(__expf(x)); }

// ---------------- LayerNorm: one 64-thread wave per row of 128 ----------------
__global__ void ln_kernel(const float* in, float* out,
                          const float* __restrict__ w, const float* __restrict__ b){
  int row = blockIdx.x; int t = threadIdx.x;
  const float* r = in + (size_t)row*D_MODEL;
  float a0 = r[t], a1 = r[t+64];
  float s = a0 + a1;
  #pragma unroll
  for (int off=32; off; off>>=1) s += __shfl_xor(s, off);
  float mu = s * (1.f/128.f);
  float d0 = a0-mu, d1 = a1-mu;
  float v = d0*d0 + d1*d1;
  #pragma unroll
  for (int off=32; off; off>>=1) v += __shfl_xor(v, off);
  float rs = rsqrtf(v*(1.f/128.f) + LN_EPS);
  out[(size_t)row*D_MODEL + t]    = d0*rs*w[t]    + b[t];
  out[(size_t)row*D_MODEL + t+64] = d1*rs*w[t+64] + b[t+64];
}

// ---------------- Generic fp32 tiled GEMM: C[M,N] = act(A[M,K]@B[K,N] + bias) ----------------
// BM=BN=64, BK=16, 256 threads, 4x4 per thread. A is contiguous (lda=K).
template<bool BIAS, bool SOFTPLUS, bool ACCUM>
__global__ __launch_bounds__(256) void gemm_kernel(
    const float* __restrict__ A, const float* __restrict__ B,
    const float* __restrict__ bias, float* C,
    int M, int N, int K, int ldb, int ldc){
  __shared__ float As[16][68];   // transposed: As[k][m]
  __shared__ float Bs[16][68];
  int tid = threadIdx.x;
  int tx = tid & 15, ty = tid >> 4;
  int row0 = blockIdx.y * 64, col0 = blockIdx.x * 64;
  int mA = tid >> 2, kA = (tid & 3) << 2;
  int kB = tid >> 4, nB = (tid & 15) << 2;
  float acc[4][4] = {};
  for (int k0 = 0; k0 < K; k0 += 16){
    float4 av = *(const float4*)(A + (size_t)(row0+mA)*K + k0 + kA);
    As[kA+0][mA]=av.x; As[kA+1][mA]=av.y; As[kA+2][mA]=av.z; As[kA+3][mA]=av.w;
    if (col0 + 64 <= N){
      float4 bv = *(const float4*)(B + (size_t)(k0+kB)*ldb + col0 + nB);
      Bs[kB][nB+0]=bv.x; Bs[kB][nB+1]=bv.y; Bs[kB][nB+2]=bv.z; Bs[kB][nB+3]=bv.w;
    } else {
      #pragma unroll
      for (int j=0;j<4;j++){
        int c = col0+nB+j;
        Bs[kB][nB+j] = (c < N) ? B[(size_t)(k0+kB)*ldb + c] : 0.f;
      }
    }
    __syncthreads();
    #pragma unroll
    for (int kk=0; kk<16; kk++){
      float4 a4 = *(const float4*)&As[kk][ty<<2];
      float4 b4 = *(const float4*)&Bs[kk][tx<<2];
      float ar[4] = {a4.x,a4.y,a4.z,a4.w};
      float br[4] = {b4.x,b4.y,b4.z,b4.w};
      #pragma unroll
      for (int i=0;i<4;i++)
        #pragma unroll
        for (int j=0;j<4;j++)
          acc[i][j] = fmaf(ar[i], br[j], acc[i][j]);
    }
    __syncthreads();
  }
  #pragma unroll
  for (int i=0;i<4;i++){
    int r = row0 + (ty<<2) + i;
    #pragma unroll
    for (int j=0;j<4;j++){
      int c = col0 + (tx<<2) + j;
      if (c < N){
        float v = acc[i][j];
        if (BIAS) v += bias[c];
        if (SOFTPLUS) v = softplusf(v);
        float* p = C + (size_t)r*ldc + c;
        if (ACCUM) *p += v; else *p = v;
      }
    }
  }
}

// ---------------- Causal depthwise conv1d(K=4) + bias + silu ----------------
// reads xi_raw = first 256 cols of xz (stride 512), writes xi (stride 256)
__global__ void conv_silu_kernel(const float* __restrict__ xz, const float* __restrict__ cw,
                                 const float* __restrict__ cb, float* __restrict__ xi){
  int idx = blockIdx.x*256 + threadIdx.x;      // over NTOK*256
  int d = idx & (D_INNER-1);
  int t = idx >> 8;
  int l = t & (SEQ-1);
  int b = t >> 10;
  float acc = cb[d];
  #pragma unroll
  for (int k=0;k<D_CONVK;k++){
    int ls = l + k - (D_CONVK-1);
    if (ls >= 0)
      acc = fmaf(xz[((size_t)(b*SEQ + ls))*(2*D_INNER) + d], cw[d*D_CONVK + k], acc);
  }
  xi[idx] = siluf(acc);
}

// ---------------- Selective scan: 1 thread per (b,d), 16 states in regs ----------------
// yout may alias delta (each (t,d) read before written by its own thread)
__global__ void scan_kernel(const float* delta, const float* __restrict__ xi,
                            const float* __restrict__ Bm, const float* __restrict__ xz,
                            const float* __restrict__ A_log, const float* __restrict__ Dp,
                            float* yout){
  int b = blockIdx.x >> 2;
  int d = ((blockIdx.x & 3) << 6) + threadIdx.x;
  float Aa[D_STATE];
  #pragma unroll
  for (int n=0;n<D_STATE;n++) Aa[n] = -__expf(A_log[d*D_STATE + n]);
  float Dv = Dp[d];
  float s[D_STATE] = {};
  size_t tokbase = (size_t)b * SEQ;
  for (int l=0; l<SEQ; l++){
    size_t t = tokbase + l;
    float dlt = delta[t*D_INNER + d];
    float xv  = xi[t*D_INNER + d];
    const float4* bmr = (const float4*)(Bm + t*D_STATE);
    float4 q0=bmr[0], q1=bmr[1], q2=bmr[2], q3=bmr[3];
    float bm[D_STATE] = {q0.x,q0.y,q0.z,q0.w, q1.x,q1.y,q1.z,q1.w,
                         q2.x,q2.y,q2.z,q2.w, q3.x,q3.y,q3.z,q3.w};
    float dx = dlt * xv;
    float y = 0.f;
    #pragma unroll
    for (int n=0;n<D_STATE;n++){
      float da = __expf(dlt * Aa[n]);
      s[n] = fmaf(da, s[n], dx * bm[n]);
      y = fmaf(s[n], bm[n], y);
    }
    float zv = xz[t*(2*D_INNER) + D_INNER + d];
    yout[t*D_INNER + d] = (y + Dv*xv) * siluf(zv);
  }
}

extern "C" void kernel_launch(void* const* d_in, const int* in_sizes, int n_in,
                              void* d_out, int out_size, void* d_ws, size_t ws_size,
                              hipStream_t stream){
  const float* x      = (const float*)d_in[0];
  const float* inp_w  = (const float*)d_in[1];
  const float* inp_b  = (const float*)d_in[2];
  const float* ln_w   = (const float*)d_in[3];
  const float* ln_b   = (const float*)d_in[4];
  const float* in_w   = (const float*)d_in[5];
  const float* conv_w = (const float*)d_in[6];
  const float* conv_b = (const float*)d_in[7];
  const float* xproj_w= (const float*)d_in[8];
  const float* dt_w   = (const float*)d_in[9];
  const float* dt_b   = (const float*)d_in[10];
  const float* A_log  = (const float*)d_in[11];
  const float* Dp     = (const float*)d_in[12];
  const float* out_w  = (const float*)d_in[13];
  const float* fn_w   = (const float*)d_in[14];
  const float* fn_b   = (const float*)d_in[15];

  float* h  = (float*)d_out;            // (NTOK,128) — residual stream
  float* ws = (float*)d_ws;
  float* xz    = ws;                              // NTOK*512
  float* xi    = xz    + (size_t)NTOK*512;        // NTOK*256
  float* delta = xi    + (size_t)NTOK*256;        // NTOK*256 (y overwrites)
  float* Bm    = delta + (size_t)NTOK*256;        // NTOK*16
  float* hn    = Bm    + (size_t)NTOK*16;         // NTOK*128

  // h = x @ inp_w + inp_b     (K=64, N=128)
  gemm_kernel<true,false,false><<<dim3(2, NTOK/64), 256, 0, stream>>>(
      x, inp_w, inp_b, h, NTOK, 128, 64, 128, 128);

  for (int i=0;i<N_LAYERS;i++){
    ln_kernel<<<NTOK, 64, 0, stream>>>(h, hn, ln_w + i*D_MODEL, ln_b + i*D_MODEL);
    // xz = hn @ in_w          (K=128, N=512)
    gemm_kernel<false,false,false><<<dim3(8, NTOK/64), 256, 0, stream>>>(
        hn, in_w + (size_t)i*D_MODEL*2*D_INNER, nullptr, xz, NTOK, 2*D_INNER, D_MODEL, 2*D_INNER, 2*D_INNER);
    conv_silu_kernel<<<NTOK, 256, 0, stream>>>(
        xz, conv_w + i*D_INNER*D_CONVK, conv_b + i*D_INNER, xi);
    // Bm = xi @ xproj_w[:,16:32]   (K=256, N=16, ldb=32)
    gemm_kernel<false,false,false><<<dim3(1, NTOK/64), 256, 0, stream>>>(
        xi, xproj_w + (size_t)i*D_INNER*2*D_STATE + D_STATE, nullptr, Bm, NTOK, D_STATE, D_INNER, 2*D_STATE, D_STATE);
    // delta = softplus(xi @ dt_w + dt_b)  (K=256, N=256)
    gemm_kernel<true,true,false><<<dim3(4, NTOK/64), 256, 0, stream>>>(
        xi, dt_w + (size_t)i*D_INNER*D_INNER, dt_b + i*D_INNER, delta, NTOK, D_INNER, D_INNER, D_INNER, D_INNER);
    // scan + elementwise epilogue; y overwrites delta
    scan_kernel<<<BATCH*4, 64, 0, stream>>>(
        delta, xi, Bm, xz, A_log + i*D_INNER*D_STATE, Dp + i*D_INNER, delta);
    // h += y @ out_w          (K=256, N=128)
    gemm_kernel<false,false,true><<<dim3(2, NTOK/64), 256, 0, stream>>>(
        delta, out_w + (size_t)i*D_INNER*D_MODEL, nullptr, h, NTOK, D_MODEL, D_INNER, D_MODEL, D_MODEL);
  }
  ln_kernel<<<NTOK, 64, 0, stream>>>(h, h, fn_w, fn_b);
}

// Round 2
// 488.166 us; speedup vs baseline: 2.6383x; 2.6383x over previous
//
#include <hip/hip_runtime.h>
#include <hip/hip_bf16.h>
#include <cstddef>

#define BATCH   16
#define SEQ     1024
#define D_MODEL 128
#define D_STATE 16
#define D_CONVK 4
#define D_INNER 256
#define N_LAYERS 2
#define NTOK    (BATCH*SEQ)   /* 16384 */
#define LN_EPS  1e-5f
#define CL      64            /* scan chunk length */
#define NC      16            /* chunks per sequence */

__device__ __forceinline__ float siluf(float v){ return v / (1.f + __expf(-v)); }
__device__ __forceinline__ float softplusf(float x){ return x > 20.f ? x : log1pf(__expf(x)); }

// ---------------- LayerNorm: one 64-thread wave per row of 128 ----------------
__global__ void ln_kernel(const float* __restrict__ in, float* __restrict__ out,
                          const float* __restrict__ w, const float* __restrict__ b){
  int row = blockIdx.x; int t = threadIdx.x;
  const float* r = in + (size_t)row*D_MODEL;
  float a0 = r[t], a1 = r[t+64];
  float s = a0 + a1;
  #pragma unroll
  for (int off=32; off; off>>=1) s += __shfl_xor(s, off);
  float mu = s * (1.f/128.f);
  float d0 = a0-mu, d1 = a1-mu;
  float v = d0*d0 + d1*d1;
  #pragma unroll
  for (int off=32; off; off>>=1) v += __shfl_xor(v, off);
  float rs = rsqrtf(v*(1.f/128.f) + LN_EPS);
  out[(size_t)row*D_MODEL + t]    = d0*rs*w[t]    + b[t];
  out[(size_t)row*D_MODEL + t+64] = d1*rs*w[t+64] + b[t+64];
}

// ---------------- Generic fp32 tiled GEMM: C[M,N] = act(A[M,K]@B[K,N] + bias) ----------------
template<bool BIAS, bool SOFTPLUS, bool ACCUM>
__global__ __launch_bounds__(256) void gemm_kernel(
    const float* __restrict__ A, const float* __restrict__ B,
    const float* __restrict__ bias, float* C,
    int M, int N, int K, int ldb, int ldc){
  __shared__ float As[16][68];   // transposed: As[k][m]
  __shared__ float Bs[16][68];
  int tid = threadIdx.x;
  int tx = tid & 15, ty = tid >> 4;
  int row0 = blockIdx.y * 64, col0 = blockIdx.x * 64;
  int mA = tid >> 2, kA = (tid & 3) << 2;
  int kB = tid >> 4, nB = (tid & 15) << 2;
  float acc[4][4] = {};
  for (int k0 = 0; k0 < K; k0 += 16){
    float4 av = *(const float4*)(A + (size_t)(row0+mA)*K + k0 + kA);
    As[kA+0][mA]=av.x; As[kA+1][mA]=av.y; As[kA+2][mA]=av.z; As[kA+3][mA]=av.w;
    if (col0 + 64 <= N){
      float4 bv = *(const float4*)(B + (size_t)(k0+kB)*ldb + col0 + nB);
      Bs[kB][nB+0]=bv.x; Bs[kB][nB+1]=bv.y; Bs[kB][nB+2]=bv.z; Bs[kB][nB+3]=bv.w;
    } else {
      #pragma unroll
      for (int j=0;j<4;j++){
        int c = col0+nB+j;
        Bs[kB][nB+j] = (c < N) ? B[(size_t)(k0+kB)*ldb + c] : 0.f;
      }
    }
    __syncthreads();
    #pragma unroll
    for (int kk=0; kk<16; kk++){
      float4 a4 = *(const float4*)&As[kk][ty<<2];
      float4 b4 = *(const float4*)&Bs[kk][tx<<2];
      float ar[4] = {a4.x,a4.y,a4.z,a4.w};
      float br[4] = {b4.x,b4.y,b4.z,b4.w};
      #pragma unroll
      for (int i=0;i<4;i++)
        #pragma unroll
        for (int j=0;j<4;j++)
          acc[i][j] = fmaf(ar[i], br[j], acc[i][j]);
    }
    __syncthreads();
  }
  #pragma unroll
  for (int i=0;i<4;i++){
    int r = row0 + (ty<<2) + i;
    #pragma unroll
    for (int j=0;j<4;j++){
      int c = col0 + (tx<<2) + j;
      if (c < N){
        float v = acc[i][j];
        if (BIAS) v += bias[c];
        if (SOFTPLUS) v = softplusf(v);
        float* p = C + (size_t)r*ldc + c;
        if (ACCUM) *p += v; else *p = v;
      }
    }
  }
}

// ---------------- Causal depthwise conv1d(K=4) + bias + silu ----------------
__global__ void conv_silu_kernel(const float* __restrict__ xr, const float* __restrict__ cw,
                                 const float* __restrict__ cb, float* __restrict__ xi){
  int idx = blockIdx.x*256 + threadIdx.x;      // over NTOK*256
  int d = idx & (D_INNER-1);
  int t = idx >> 8;
  int l = t & (SEQ-1);
  int bs = t - l;                               // b*SEQ
  float acc = cb[d];
  #pragma unroll
  for (int k=0;k<D_CONVK;k++){
    int ls = l + k - (D_CONVK-1);
    if (ls >= 0)
      acc = fmaf(xr[(size_t)(bs + ls)*D_INNER + d], cw[d*D_CONVK + k], acc);
  }
  xi[idx] = siluf(acc);
}

// ---------------- Chunked selective scan ----------------
// Phase 1: per (b,chunk,d) thread — local scan from zero; store s_end + sum(delta)
__global__ __launch_bounds__(256) void scan_p1(
    const float* __restrict__ delta, const float* __restrict__ xi,
    const float* __restrict__ Bm, const float* __restrict__ A_log,
    float* __restrict__ cs, float* __restrict__ sumdlt){
  int bc = blockIdx.x;               // b*NC + c
  int c = bc & (NC-1);
  int b = bc >> 4;
  int d = threadIdx.x;
  float Aa[D_STATE];
  #pragma unroll
  for (int n=0;n<D_STATE;n++) Aa[n] = -__expf(A_log[d*D_STATE + n]);
  float s[D_STATE] = {};
  float sd = 0.f;
  size_t t0 = (size_t)b*SEQ + (size_t)c*CL;
  #pragma unroll 4
  for (int l=0; l<CL; l++){
    size_t t = t0 + l;
    float dlt = delta[t*D_INNER + d];
    float xv  = xi[t*D_INNER + d];
    const float4* bmr = (const float4*)(Bm + t*D_STATE);
    float4 q0=bmr[0], q1=bmr[1], q2=bmr[2], q3=bmr[3];
    float bm[D_STATE] = {q0.x,q0.y,q0.z,q0.w, q1.x,q1.y,q1.z,q1.w,
                         q2.x,q2.y,q2.z,q2.w, q3.x,q3.y,q3.z,q3.w};
    sd += dlt;
    float dx = dlt * xv;
    #pragma unroll
    for (int n=0;n<D_STATE;n++)
      s[n] = fmaf(__expf(dlt * Aa[n]), s[n], dx * bm[n]);
  }
  float4* out = (float4*)(cs + ((size_t)bc*D_INNER + d)*D_STATE);
  out[0] = make_float4(s[0],s[1],s[2],s[3]);
  out[1] = make_float4(s[4],s[5],s[6],s[7]);
  out[2] = make_float4(s[8],s[9],s[10],s[11]);
  out[3] = make_float4(s[12],s[13],s[14],s[15]);
  sumdlt[(size_t)bc*D_INNER + d] = sd;
}

// Phase 2: per (b,d) thread — combine chunks; overwrite cs with incoming state per chunk
__global__ __launch_bounds__(256) void scan_p2(
    const float* __restrict__ A_log, float* __restrict__ cs,
    const float* __restrict__ sumdlt){
  int b = blockIdx.x;                 // 16 blocks
  int d = threadIdx.x;                // 256 threads
  float Aa[D_STATE];
  #pragma unroll
  for (int n=0;n<D_STATE;n++) Aa[n] = -__expf(A_log[d*D_STATE + n]);
  float s[D_STATE] = {};
  #pragma unroll
  for (int c=0;c<NC;c++){
    size_t base = ((size_t)(b*NC + c)*D_INNER + d)*D_STATE;
    float4* p = (float4*)(cs + base);
    float4 e0=p[0], e1=p[1], e2=p[2], e3=p[3];
    float se[D_STATE] = {e0.x,e0.y,e0.z,e0.w, e1.x,e1.y,e1.z,e1.w,
                         e2.x,e2.y,e2.z,e2.w, e3.x,e3.y,e3.z,e3.w};
    float sd = sumdlt[(size_t)(b*NC + c)*D_INNER + d];
    float sin_[D_STATE];
    #pragma unroll
    for (int n=0;n<D_STATE;n++){
      sin_[n] = s[n];
      s[n] = fmaf(__expf(Aa[n]*sd), s[n], se[n]);
    }
    p[0] = make_float4(sin_[0],sin_[1],sin_[2],sin_[3]);
    p[1] = make_float4(sin_[4],sin_[5],sin_[6],sin_[7]);
    p[2] = make_float4(sin_[8],sin_[9],sin_[10],sin_[11]);
    p[3] = make_float4(sin_[12],sin_[13],sin_[14],sin_[15]);
  }
}

// Phase 3: per (b,chunk,d) thread — rescan from incoming state, fused epilogue
__global__ __launch_bounds__(256) void scan_p3(
    const float* __restrict__ delta, const float* __restrict__ xi,
    const float* __restrict__ Bm, const float* __restrict__ zbuf,
    const float* __restrict__ A_log, const float* __restrict__ Dp,
    const float* __restrict__ cs, float* __restrict__ ybuf){
  int bc = blockIdx.x;
  int c = bc & (NC-1);
  int b = bc >> 4;
  int d = threadIdx.x;
  float Aa[D_STATE];
  #pragma unroll
  for (int n=0;n<D_STATE;n++) Aa[n] = -__expf(A_log[d*D_STATE + n]);
  float Dv = Dp[d];
  const float4* sp = (const float4*)(cs + ((size_t)bc*D_INNER + d)*D_STATE);
  float4 s0=sp[0], s1=sp[1], s2=sp[2], s3=sp[3];
  float s[D_STATE] = {s0.x,s0.y,s0.z,s0.w, s1.x,s1.y,s1.z,s1.w,
                      s2.x,s2.y,s2.z,s2.w, s3.x,s3.y,s3.z,s3.w};
  size_t t0 = (size_t)b*SEQ + (size_t)c*CL;
  #pragma unroll 4
  for (int l=0; l<CL; l++){
    size_t t = t0 + l;
    float dlt = delta[t*D_INNER + d];
    float xv  = xi[t*D_INNER + d];
    float zv  = zbuf[t*D_INNER + d];
    const float4* bmr = (const float4*)(Bm + t*D_STATE);
    float4 q0=bmr[0], q1=bmr[1], q2=bmr[2], q3=bmr[3];
    float bm[D_STATE] = {q0.x,q0.y,q0.z,q0.w, q1.x,q1.y,q1.z,q1.w,
                         q2.x,q2.y,q2.z,q2.w, q3.x,q3.y,q3.z,q3.w};
    float dx = dlt * xv;
    float y = 0.f;
    #pragma unroll
    for (int n=0;n<D_STATE;n++){
      s[n] = fmaf(__expf(dlt * Aa[n]), s[n], dx * bm[n]);
      y = fmaf(s[n], bm[n], y);
    }
    ybuf[t*D_INNER + d] = (y + Dv*xv) * siluf(zv);
  }
}

extern "C" void kernel_launch(void* const* d_in, const int* in_sizes, int n_in,
                              void* d_out, int out_size, void* d_ws, size_t ws_size,
                              hipStream_t stream){
  const float* x      = (const float*)d_in[0];
  const float* inp_w  = (const float*)d_in[1];
  const float* inp_b  = (const float*)d_in[2];
  const float* ln_w   = (const float*)d_in[3];
  const float* ln_b   = (const float*)d_in[4];
  const float* in_w   = (const float*)d_in[5];
  const float* conv_w = (const float*)d_in[6];
  const float* conv_b = (const float*)d_in[7];
  const float* xproj_w= (const float*)d_in[8];
  const float* dt_w   = (const float*)d_in[9];
  const float* dt_b   = (const float*)d_in[10];
  const float* A_log  = (const float*)d_in[11];
  const float* Dp     = (const float*)d_in[12];
  const float* out_w  = (const float*)d_in[13];
  const float* fn_w   = (const float*)d_in[14];
  const float* fn_b   = (const float*)d_in[15];

  float* h  = (float*)d_out;                      // (NTOK,128) residual stream
  float* ws = (float*)d_ws;
  float* xiraw = ws;                              // NTOK*256  (dies after conv; reused as ybuf)
  float* zbuf  = xiraw + (size_t)NTOK*256;        // NTOK*256
  float* xi    = zbuf  + (size_t)NTOK*256;        // NTOK*256
  float* delta = xi    + (size_t)NTOK*256;        // NTOK*256
  float* Bm    = delta + (size_t)NTOK*256;        // NTOK*16
  float* hn    = Bm    + (size_t)NTOK*16;         // NTOK*128 (ln out; scan temps reuse)
  float* ybuf  = xiraw;                           // overlay (xiraw dead after conv)
  float* cs     = hn;                             // 16*NC*256*16 = 1.05M floats
  float* sumdlt = hn + (size_t)16*NC*D_INNER*D_STATE;  // 65K floats

  // h = x @ inp_w + inp_b     (K=64, N=128)
  gemm_kernel<true,false,false><<<dim3(2, NTOK/64), 256, 0, stream>>>(
      x, inp_w, inp_b, h, NTOK, 128, 64, 128, 128);

  for (int i=0;i<N_LAYERS;i++){
    ln_kernel<<<NTOK, 64, 0, stream>>>(h, hn, ln_w + i*D_MODEL, ln_b + i*D_MODEL);
    // split in-proj: xiraw = hn @ in_w[:, :256], zbuf = hn @ in_w[:, 256:]
    const float* Bw = in_w + (size_t)i*D_MODEL*2*D_INNER;
    gemm_kernel<false,false,false><<<dim3(4, NTOK/64), 256, 0, stream>>>(
        hn, Bw, nullptr, xiraw, NTOK, D_INNER, D_MODEL, 2*D_INNER, D_INNER);
    gemm_kernel<false,false,false><<<dim3(4, NTOK/64), 256, 0, stream>>>(
        hn, Bw + D_INNER, nullptr, zbuf, NTOK, D_INNER, D_MODEL, 2*D_INNER, D_INNER);
    conv_silu_kernel<<<NTOK, 256, 0, stream>>>(
        xiraw, conv_w + i*D_INNER*D_CONVK, conv_b + i*D_INNER, xi);
    // Bm = xi @ xproj_w[:,16:32]   (K=256, N=16, ldb=32)
    gemm_kernel<false,false,false><<<dim3(1, NTOK/64), 256, 0, stream>>>(
        xi, xproj_w + (size_t)i*D_INNER*2*D_STATE + D_STATE, nullptr, Bm,
        NTOK, D_STATE, D_INNER, 2*D_STATE, D_STATE);
    // delta = softplus(xi @ dt_w + dt_b)  (K=256, N=256)
    gemm_kernel<true,true,false><<<dim3(4, NTOK/64), 256, 0, stream>>>(
        xi, dt_w + (size_t)i*D_INNER*D_INNER, dt_b + i*D_INNER, delta,
        NTOK, D_INNER, D_INNER, D_INNER, D_INNER);
    // chunked scan
    const float* Al = A_log + (size_t)i*D_INNER*D_STATE;
    scan_p1<<<BATCH*NC, 256, 0, stream>>>(delta, xi, Bm, Al, cs, sumdlt);
    scan_p2<<<BATCH, 256, 0, stream>>>(Al, cs, sumdlt);
    scan_p3<<<BATCH*NC, 256, 0, stream>>>(delta, xi, Bm, zbuf, Al,
                                          Dp + i*D_INNER, cs, ybuf);
    // h += y @ out_w          (K=256, N=128)
    gemm_kernel<false,false,true><<<dim3(2, NTOK/64), 256, 0, stream>>>(
        ybuf, out_w + (size_t)i*D_INNER*D_MODEL, nullptr, h, NTOK, D_MODEL, D_INNER, D_MODEL, D_MODEL);
  }
  ln_kernel<<<NTOK, 64, 0, stream>>>(h, h, fn_w, fn_b);
}

// Round 3
// 348.648 us; speedup vs baseline: 3.6941x; 1.4002x over previous
//
#include <hip/hip_runtime.h>
#include <hip/hip_bf16.h>
#include <cstddef>

#define BATCH   16
#define SEQ     1024
#define D_MODEL 128
#define D_STATE 16
#define D_CONVK 4
#define D_INNER 256
#define N_LAYERS 2
#define NTOK    (BATCH*SEQ)   /* 16384 */
#define LN_EPS  1e-5f
#define CL      64            /* scan chunk length */
#define NC      16            /* chunks per sequence */

typedef __attribute__((ext_vector_type(8))) short bf16x8;
typedef __attribute__((ext_vector_type(4))) float f32x4;

__device__ __forceinline__ float siluf(float v){ return v / (1.f + __expf(-v)); }
__device__ __forceinline__ float softplusf(float x){ return x > 20.f ? x : log1pf(__expf(x)); }
__device__ __forceinline__ short f2b(float f){
  __hip_bfloat16 h = __float2bfloat16(f);
  return *reinterpret_cast<short*>(&h);
}

// ---------------- weight transpose+convert: dst[n*K+k] = bf16(src[k*ldsrc + coff + n]) ----------------
__global__ void convT_kernel(const float* __restrict__ src, __hip_bfloat16* __restrict__ dst,
                             int K, int N, int ldsrc, int coff){
  int idx = blockIdx.x*256 + threadIdx.x;
  if (idx >= K*N) return;
  int k = idx % K, n = idx / K;
  dst[(size_t)n*K + k] = __float2bfloat16(src[(size_t)k*ldsrc + coff + n]);
}

// ---------------- LayerNorm: one 64-thread wave per row of 128 ----------------
template<bool OUT_BF16>
__global__ void ln_kernel(const float* __restrict__ in, void* __restrict__ outp,
                          const float* __restrict__ w, const float* __restrict__ b){
  int row = blockIdx.x; int t = threadIdx.x;
  const float* r = in + (size_t)row*D_MODEL;
  float a0 = r[t], a1 = r[t+64];
  float s = a0 + a1;
  #pragma unroll
  for (int off=32; off; off>>=1) s += __shfl_xor(s, off);
  float mu = s * (1.f/128.f);
  float d0 = a0-mu, d1 = a1-mu;
  float v = d0*d0 + d1*d1;
  #pragma unroll
  for (int off=32; off; off>>=1) v += __shfl_xor(v, off);
  float rs = rsqrtf(v*(1.f/128.f) + LN_EPS);
  float o0 = d0*rs*w[t] + b[t];
  float o1 = d1*rs*w[t+64] + b[t+64];
  if (OUT_BF16){
    __hip_bfloat16* out = (__hip_bfloat16*)outp;
    out[(size_t)row*D_MODEL + t]    = __float2bfloat16(o0);
    out[(size_t)row*D_MODEL + t+64] = __float2bfloat16(o1);
  } else {
    float* out = (float*)outp;
    out[(size_t)row*D_MODEL + t]    = o0;
    out[(size_t)row*D_MODEL + t+64] = o1;
  }
}

// ---------------- fp32 tiled GEMM (input proj only) ----------------
template<bool BIAS>
__global__ __launch_bounds__(256) void gemm_kernel(
    const float* __restrict__ A, const float* __restrict__ B,
    const float* __restrict__ bias, float* C,
    int M, int N, int K, int ldb, int ldc){
  __shared__ float As[16][68];
  __shared__ float Bs[16][68];
  int tid = threadIdx.x;
  int tx = tid & 15, ty = tid >> 4;
  int row0 = blockIdx.y * 64, col0 = blockIdx.x * 64;
  int mA = tid >> 2, kA = (tid & 3) << 2;
  int kB = tid >> 4, nB = (tid & 15) << 2;
  float acc[4][4] = {};
  for (int k0 = 0; k0 < K; k0 += 16){
    float4 av = *(const float4*)(A + (size_t)(row0+mA)*K + k0 + kA);
    As[kA+0][mA]=av.x; As[kA+1][mA]=av.y; As[kA+2][mA]=av.z; As[kA+3][mA]=av.w;
    float4 bv = *(const float4*)(B + (size_t)(k0+kB)*ldb + col0 + nB);
    Bs[kB][nB+0]=bv.x; Bs[kB][nB+1]=bv.y; Bs[kB][nB+2]=bv.z; Bs[kB][nB+3]=bv.w;
    __syncthreads();
    #pragma unroll
    for (int kk=0; kk<16; kk++){
      float4 a4 = *(const float4*)&As[kk][ty<<2];
      float4 b4 = *(const float4*)&Bs[kk][tx<<2];
      float ar[4] = {a4.x,a4.y,a4.z,a4.w};
      float br[4] = {b4.x,b4.y,b4.z,b4.w};
      #pragma unroll
      for (int i=0;i<4;i++)
        #pragma unroll
        for (int j=0;j<4;j++)
          acc[i][j] = fmaf(ar[i], br[j], acc[i][j]);
    }
    __syncthreads();
  }
  #pragma unroll
  for (int i=0;i<4;i++){
    int r = row0 + (ty<<2) + i;
    #pragma unroll
    for (int j=0;j<4;j++){
      int c = col0 + (tx<<2) + j;
      float v = acc[i][j];
      if (BIAS) v += bias[c];
      C[(size_t)r*ldc + c] = v;
    }
  }
}

// ---------------- bf16 MFMA GEMM: C[M,Nvalid] = act(A @ Bt^T + bias) ----------------
// A: row-major [M][lda] (bf16, or fp32 converted in staging). Bt: bf16 [N][K] (pre-transposed).
// BM=BN=64, BK=32, 256 threads = 4 waves (2x2 of 32x32 each).
template<bool A_FP32, bool BIAS, bool SOFTPLUS, bool ACCUM>
__global__ __launch_bounds__(256) void mfma_gemm(
    const void* __restrict__ Aptr, const __hip_bfloat16* __restrict__ Bt,
    const float* __restrict__ bias, float* __restrict__ C,
    int lda, int K, int Nvalid, int ldc){
  __shared__ __align__(16) short As[64][40];
  __shared__ __align__(16) short Bs[64][40];
  int tid = threadIdx.x;
  int row0 = blockIdx.y * 64, col0 = blockIdx.x * 64;
  int r = tid >> 2, seg = tid & 3;          // staging: row 0..63, k-seg 0..3
  int lane = tid & 63, w = tid >> 6;
  int wr = (w >> 1) * 32, wc = (w & 1) * 32;
  int fr = lane & 15, fq = lane >> 4;       // fragment row/col & k-quad
  f32x4 acc00 = {}, acc01 = {}, acc10 = {}, acc11 = {};
  for (int k0 = 0; k0 < K; k0 += 32){
    // stage A
    if (A_FP32){
      const float* Af = (const float*)Aptr + (size_t)(row0+r)*lda + k0 + seg*8;
      float4 a0 = *(const float4*)Af;
      float4 a1 = *(const float4*)(Af+4);
      bf16x8 v;
      v[0]=f2b(a0.x); v[1]=f2b(a0.y); v[2]=f2b(a0.z); v[3]=f2b(a0.w);
      v[4]=f2b(a1.x); v[5]=f2b(a1.y); v[6]=f2b(a1.z); v[7]=f2b(a1.w);
      *(bf16x8*)&As[r][seg*8] = v;
    } else {
      const __hip_bfloat16* Ab = (const __hip_bfloat16*)Aptr + (size_t)(row0+r)*lda + k0 + seg*8;
      *(bf16x8*)&As[r][seg*8] = *(const bf16x8*)Ab;
    }
    // stage B (transposed weight, [n][k])
    bf16x8 bv = {};
    if (col0 + r < Nvalid)
      bv = *(const bf16x8*)(Bt + (size_t)(col0+r)*K + k0 + seg*8);
    *(bf16x8*)&Bs[r][seg*8] = bv;
    __syncthreads();
    bf16x8 a0 = *(bf16x8*)&As[wr + fr][fq*8];
    bf16x8 a1 = *(bf16x8*)&As[wr + 16 + fr][fq*8];
    bf16x8 b0 = *(bf16x8*)&Bs[wc + fr][fq*8];
    bf16x8 b1 = *(bf16x8*)&Bs[wc + 16 + fr][fq*8];
    acc00 = __builtin_amdgcn_mfma_f32_16x16x32_bf16(a0, b0, acc00, 0, 0, 0);
    acc01 = __builtin_amdgcn_mfma_f32_16x16x32_bf16(a0, b1, acc01, 0, 0, 0);
    acc10 = __builtin_amdgcn_mfma_f32_16x16x32_bf16(a1, b0, acc10, 0, 0, 0);
    acc11 = __builtin_amdgcn_mfma_f32_16x16x32_bf16(a1, b1, acc11, 0, 0, 0);
    __syncthreads();
  }
  f32x4 accs[2][2] = {{acc00, acc01},{acc10, acc11}};
  #pragma unroll
  for (int mr=0; mr<2; mr++){
    #pragma unroll
    for (int nc=0; nc<2; nc++){
      int gcol = col0 + wc + nc*16 + fr;
      if (gcol < Nvalid){
        float bval = BIAS ? bias[gcol] : 0.f;
        #pragma unroll
        for (int q=0; q<4; q++){
          int grow = row0 + wr + mr*16 + fq*4 + q;
          float v = accs[mr][nc][q] + bval;
          if (SOFTPLUS) v = softplusf(v);
          float* p = C + (size_t)grow*ldc + gcol;
          if (ACCUM) *p += v; else *p = v;
        }
      }
    }
  }
}

// ---------------- Causal depthwise conv1d(K=4) + bias + silu ----------------
// reads x-part of xz (stride 512), writes xi fp32 (stride 256)
__global__ void conv_silu_kernel(const float* __restrict__ xz, const float* __restrict__ cw,
                                 const float* __restrict__ cb, float* __restrict__ xi){
  int idx = blockIdx.x*256 + threadIdx.x;      // over NTOK*256
  int d = idx & (D_INNER-1);
  int t = idx >> 8;
  int l = t & (SEQ-1);
  int bs = t - l;
  float acc = cb[d];
  #pragma unroll
  for (int k=0;k<D_CONVK;k++){
    int ls = l + k - (D_CONVK-1);
    if (ls >= 0)
      acc = fmaf(xz[(size_t)(bs + ls)*(2*D_INNER) + d], cw[d*D_CONVK + k], acc);
  }
  xi[idx] = siluf(acc);
}

// ---------------- Chunked selective scan ----------------
__global__ __launch_bounds__(256) void scan_p1(
    const float* __restrict__ delta, const float* __restrict__ xi,
    const float* __restrict__ Bm, const float* __restrict__ A_log,
    float* __restrict__ cs, float* __restrict__ sumdlt){
  int bc = blockIdx.x;
  int c = bc & (NC-1);
  int b = bc >> 4;
  int d = threadIdx.x;
  float Aa[D_STATE];
  #pragma unroll
  for (int n=0;n<D_STATE;n++) Aa[n] = -__expf(A_log[d*D_STATE + n]);
  float s[D_STATE] = {};
  float sd = 0.f;
  size_t t0 = (size_t)b*SEQ + (size_t)c*CL;
  #pragma unroll 4
  for (int l=0; l<CL; l++){
    size_t t = t0 + l;
    float dlt = delta[t*D_INNER + d];
    float xv  = xi[t*D_INNER + d];
    const float4* bmr = (const float4*)(Bm + t*D_STATE);
    float4 q0=bmr[0], q1=bmr[1], q2=bmr[2], q3=bmr[3];
    float bm[D_STATE] = {q0.x,q0.y,q0.z,q0.w, q1.x,q1.y,q1.z,q1.w,
                         q2.x,q2.y,q2.z,q2.w, q3.x,q3.y,q3.z,q3.w};
    sd += dlt;
    float dx = dlt * xv;
    #pragma unroll
    for (int n=0;n<D_STATE;n++)
      s[n] = fmaf(__expf(dlt * Aa[n]), s[n], dx * bm[n]);
  }
  float4* out = (float4*)(cs + ((size_t)bc*D_INNER + d)*D_STATE);
  out[0] = make_float4(s[0],s[1],s[2],s[3]);
  out[1] = make_float4(s[4],s[5],s[6],s[7]);
  out[2] = make_float4(s[8],s[9],s[10],s[11]);
  out[3] = make_float4(s[12],s[13],s[14],s[15]);
  sumdlt[(size_t)bc*D_INNER + d] = sd;
}

__global__ __launch_bounds__(256) void scan_p2(
    const float* __restrict__ A_log, float* __restrict__ cs,
    const float* __restrict__ sumdlt){
  int b = blockIdx.x;
  int d = threadIdx.x;
  float Aa[D_STATE];
  #pragma unroll
  for (int n=0;n<D_STATE;n++) Aa[n] = -__expf(A_log[d*D_STATE + n]);
  float s[D_STATE] = {};
  #pragma unroll
  for (int c=0;c<NC;c++){
    size_t base = ((size_t)(b*NC + c)*D_INNER + d)*D_STATE;
    float4* p = (float4*)(cs + base);
    float4 e0=p[0], e1=p[1], e2=p[2], e3=p[3];
    float se[D_STATE] = {e0.x,e0.y,e0.z,e0.w, e1.x,e1.y,e1.z,e1.w,
                         e2.x,e2.y,e2.z,e2.w, e3.x,e3.y,e3.z,e3.w};
    float sd = sumdlt[(size_t)(b*NC + c)*D_INNER + d];
    float sin_[D_STATE];
    #pragma unroll
    for (int n=0;n<D_STATE;n++){
      sin_[n] = s[n];
      s[n] = fmaf(__expf(Aa[n]*sd), s[n], se[n]);
    }
    p[0] = make_float4(sin_[0],sin_[1],sin_[2],sin_[3]);
    p[1] = make_float4(sin_[4],sin_[5],sin_[6],sin_[7]);
    p[2] = make_float4(sin_[8],sin_[9],sin_[10],sin_[11]);
    p[3] = make_float4(sin_[12],sin_[13],sin_[14],sin_[15]);
  }
}

// Phase 3: rescan + fused epilogue; writes y as bf16 into x-half of xz rows (stride 1024 bf16)
__global__ __launch_bounds__(256) void scan_p3(
    const float* __restrict__ delta, const float* __restrict__ xi,
    const float* __restrict__ Bm, const float* __restrict__ xz,
    const float* __restrict__ A_log, const float* __restrict__ Dp,
    const float* __restrict__ cs, __hip_bfloat16* __restrict__ ybf){
  int bc = blockIdx.x;
  int c = bc & (NC-1);
  int b = bc >> 4;
  int d = threadIdx.x;
  float Aa[D_STATE];
  #pragma unroll
  for (int n=0;n<D_STATE;n++) Aa[n] = -__expf(A_log[d*D_STATE + n]);
  float Dv = Dp[d];
  const float4* sp = (const float4*)(cs + ((size_t)bc*D_INNER + d)*D_STATE);
  float4 s0=sp[0], s1=sp[1], s2=sp[2], s3=sp[3];
  float s[D_STATE] = {s0.x,s0.y,s0.z,s0.w, s1.x,s1.y,s1.z,s1.w,
                      s2.x,s2.y,s2.z,s2.w, s3.x,s3.y,s3.z,s3.w};
  size_t t0 = (size_t)b*SEQ + (size_t)c*CL;
  #pragma unroll 4
  for (int l=0; l<CL; l++){
    size_t t = t0 + l;
    float dlt = delta[t*D_INNER + d];
    float xv  = xi[t*D_INNER + d];
    float zv  = xz[t*(2*D_INNER) + D_INNER + d];
    const float4* bmr = (const float4*)(Bm + t*D_STATE);
    float4 q0=bmr[0], q1=bmr[1], q2=bmr[2], q3=bmr[3];
    float bm[D_STATE] = {q0.x,q0.y,q0.z,q0.w, q1.x,q1.y,q1.z,q1.w,
                         q2.x,q2.y,q2.z,q2.w, q3.x,q3.y,q3.z,q3.w};
    float dx = dlt * xv;
    float y = 0.f;
    #pragma unroll
    for (int n=0;n<D_STATE;n++){
      s[n] = fmaf(__expf(dlt * Aa[n]), s[n], dx * bm[n]);
      y = fmaf(s[n], bm[n], y);
    }
    ybf[t*1024 + d] = __float2bfloat16((y + Dv*xv) * siluf(zv));
  }
}

extern "C" void kernel_launch(void* const* d_in, const int* in_sizes, int n_in,
                              void* d_out, int out_size, void* d_ws, size_t ws_size,
                              hipStream_t stream){
  const float* x      = (const float*)d_in[0];
  const float* inp_w  = (const float*)d_in[1];
  const float* inp_b  = (const float*)d_in[2];
  const float* ln_w   = (const float*)d_in[3];
  const float* ln_b   = (const float*)d_in[4];
  const float* in_w   = (const float*)d_in[5];
  const float* conv_w = (const float*)d_in[6];
  const float* conv_b = (const float*)d_in[7];
  const float* xproj_w= (const float*)d_in[8];
  const float* dt_w   = (const float*)d_in[9];
  const float* dt_b   = (const float*)d_in[10];
  const float* A_log  = (const float*)d_in[11];
  const float* Dp     = (const float*)d_in[12];
  const float* out_w  = (const float*)d_in[13];
  const float* fn_w   = (const float*)d_in[14];
  const float* fn_b   = (const float*)d_in[15];

  float* h  = (float*)d_out;                       // (NTOK,128) residual stream
  float* ws = (float*)d_ws;
  // float-indexed layout (73.3 MB total)
  float* xz    = ws;                               // NTOK*512
  float* xi    = xz + (size_t)NTOK*512;            // NTOK*256
  float* delta = xi + (size_t)NTOK*256;            // NTOK*256
  float* Bm    = delta + (size_t)NTOK*256;         // NTOK*16
  float* scratch = Bm + (size_t)NTOK*16;           // 1,114,112 floats: hn_bf16 overlay cs+sumdlt
  __hip_bfloat16* hn_bf = (__hip_bfloat16*)scratch;        // NTOK*128 bf16
  float* cs     = scratch;                                  // 16*NC*256*16 floats
  float* sumdlt = scratch + (size_t)16*NC*D_INNER*D_STATE;  // 65536 floats
  __hip_bfloat16* wbase = (__hip_bfloat16*)(scratch + 1114112);
  __hip_bfloat16* w_inT  = wbase;                         // 2 * 512*128
  __hip_bfloat16* w_dtT  = w_inT  + 2*512*128;            // 2 * 256*256
  __hip_bfloat16* w_xpT  = w_dtT  + 2*256*256;            // 2 * 16*256
  __hip_bfloat16* w_outT = w_xpT  + 2*16*256;             // 2 * 128*256
  __hip_bfloat16* ybf = (__hip_bfloat16*)xz;              // y overlay: row stride 1024 bf16

  // ---- weight convert+transpose (all layers, up front) ----
  for (int i=0;i<N_LAYERS;i++){
    convT_kernel<<<(128*512+255)/256, 256, 0, stream>>>(
        in_w + (size_t)i*D_MODEL*2*D_INNER, w_inT + (size_t)i*512*128, 128, 512, 512, 0);
    convT_kernel<<<(256*256+255)/256, 256, 0, stream>>>(
        dt_w + (size_t)i*D_INNER*D_INNER, w_dtT + (size_t)i*256*256, 256, 256, 256, 0);
    convT_kernel<<<(256*16+255)/256, 256, 0, stream>>>(
        xproj_w + (size_t)i*D_INNER*2*D_STATE, w_xpT + (size_t)i*16*256, 256, 16, 32, 16);
    convT_kernel<<<(256*128+255)/256, 256, 0, stream>>>(
        out_w + (size_t)i*D_INNER*D_MODEL, w_outT + (size_t)i*128*256, 256, 128, 128, 0);
  }

  // h = x @ inp_w + inp_b     (fp32 path; K=64, N=128)
  gemm_kernel<true><<<dim3(2, NTOK/64), 256, 0, stream>>>(
      x, inp_w, inp_b, h, NTOK, 128, 64, 128, 128);

  for (int i=0;i<N_LAYERS;i++){
    ln_kernel<true><<<NTOK, 64, 0, stream>>>(h, hn_bf, ln_w + i*D_MODEL, ln_b + i*D_MODEL);
    // xz = hn @ in_w    (A bf16, lda=128; N=512)
    mfma_gemm<false,false,false,false><<<dim3(8, NTOK/64), 256, 0, stream>>>(
        hn_bf, w_inT + (size_t)i*512*128, nullptr, xz, 128, 128, 512, 512);
    conv_silu_kernel<<<NTOK, 256, 0, stream>>>(
        xz, conv_w + i*D_INNER*D_CONVK, conv_b + i*D_INNER, xi);
    // Bm = xi @ xproj_w[:,16:32]   (A fp32, K=256, N=16)
    mfma_gemm<true,false,false,false><<<dim3(1, NTOK/64), 256, 0, stream>>>(
        xi, w_xpT + (size_t)i*16*256, nullptr, Bm, 256, 256, 16, 16);
    // delta = softplus(xi @ dt_w + dt_b)  (A fp32, K=256, N=256)
    mfma_gemm<true,true,true,false><<<dim3(4, NTOK/64), 256, 0, stream>>>(
        xi, w_dtT + (size_t)i*256*256, dt_b + i*D_INNER, delta, 256, 256, 256, 256);
    // chunked scan
    const float* Al = A_log + (size_t)i*D_INNER*D_STATE;
    scan_p1<<<BATCH*NC, 256, 0, stream>>>(delta, xi, Bm, Al, cs, sumdlt);
    scan_p2<<<BATCH, 256, 0, stream>>>(Al, cs, sumdlt);
    scan_p3<<<BATCH*NC, 256, 0, stream>>>(delta, xi, Bm, xz, Al,
                                          Dp + i*D_INNER, cs, ybf);
    // h += y @ out_w   (A bf16 overlay, lda=1024; K=256, N=128)
    mfma_gemm<false,false,false,true><<<dim3(2, NTOK/64), 256, 0, stream>>>(
        ybf, w_outT + (size_t)i*128*256, nullptr, h, 1024, 256, 128, 128);
  }
  ln_kernel<false><<<NTOK, 64, 0, stream>>>(h, h, fn_w, fn_b);
}